// Round 1
// baseline (740.787 us; speedup 1.0000x reference)
//
#include <hip/hip_runtime.h>

#define DEVI __device__ __forceinline__

typedef __attribute__((ext_vector_type(4))) float  f32x4;
typedef __attribute__((ext_vector_type(8))) short  s16x8;
typedef __attribute__((ext_vector_type(4))) short  s16x4;
typedef __attribute__((ext_vector_type(8))) __bf16 bf16x8;

constexpr int  Cc  = 256;
constexpr int  Nn  = 12288;
constexpr int  NP  = 12296;          // padded rows per batch (4 + 12288 + 4)
constexpr long TOK = 98304;          // B*D*N

DEVI short f2bf(float f) {           // fp32 -> bf16 (RTNE), bits as short
  unsigned u = __builtin_bit_cast(unsigned, f);
  u += 0x7fffu + ((u >> 16) & 1u);
  return (short)(u >> 16);
}

DEVI f32x4 MFMA(s16x8 a, s16x8 b, f32x4 c) {
  return __builtin_amdgcn_mfma_f32_16x16x32_bf16(
      __builtin_bit_cast(bf16x8, a), __builtin_bit_cast(bf16x8, b), c, 0, 0, 0);
}

DEVI void gld16(const void* g, void* l) {   // global -> LDS, 16B/lane, linear dest
  __builtin_amdgcn_global_load_lds(
      (const __attribute__((address_space(1))) void*)g,
      (__attribute__((address_space(3))) void*)l, 16, 0, 0);
}

// Stage a [128][32] bf16 tile into LDS. Wave w stages segments s=w*2, w*2+1
// (16 rows each). Lane covers row s*16+(lane>>2), col-chunk (lane&3)*8.
DEVI void stage_tile(const short* __restrict__ base, long row0, int ld, int k0,
                     short (*dst)[32], int w, int lane) {
#pragma unroll
  for (int c = 0; c < 2; ++c) {
    int s = w * 2 + c;
    const short* g = base + (row0 + s * 16 + (lane >> 2)) * (long)ld + k0 + (lane & 3) * 8;
    gld16(g, &dst[s * 16][0]);
  }
}

// ---------------- weight prep + halo-pad zeroing (one launch) ----------------
__global__ void prep_k(const float* __restrict__ qkv_w, const float* __restrict__ proj_w,
                       const float* __restrict__ fc1_w, const float* __restrict__ fc2_w,
                       const float* __restrict__ conv_w,
                       short* __restrict__ qkvWt, short* __restrict__ projWt,
                       short* __restrict__ fc1Wt, short* __restrict__ fc2Wt,
                       short* __restrict__ convWt, short* __restrict__ hp) {
  int idx = blockIdx.x * 256 + threadIdx.x;
  if (idx < 196608) {                 // qkvWt [768][256] <- qkv_w (256,768)
    int o = idx >> 8, i = idx & 255;
    qkvWt[idx] = f2bf(qkv_w[i * 768 + o]);
    return;
  }
  idx -= 196608;
  if (idx < 65536) {                  // projWt [256][256]
    int o = idx >> 8, i = idx & 255;
    projWt[idx] = f2bf(proj_w[i * 256 + o]);
    return;
  }
  idx -= 65536;
  if (idx < 262144) {                 // fc1Wt [1024][256]
    int o = idx >> 8, i = idx & 255;
    fc1Wt[idx] = f2bf(fc1_w[i * 1024 + o]);
    return;
  }
  idx -= 262144;
  if (idx < 262144) {                 // fc2Wt [256][1024]
    int o = idx >> 10, i = idx & 1023;
    fc2Wt[idx] = f2bf(fc2_w[i * 256 + o]);
    return;
  }
  idx -= 262144;
  if (idx < 589824) {                 // convWt [9][256 co][256 ci] <- conv_w (co,ci,k)
    int k = idx >> 16, co = (idx >> 8) & 255, ci = idx & 255;
    convWt[idx] = f2bf(conv_w[co * 2304 + ci * 9 + k]);
    return;
  }
  idx -= 589824;
  if (idx < 16384) {                  // zero halo pads of hp
    int b = idx >> 11, rem = idx & 2047;
    int rs = rem >> 8, ch = rem & 255;
    int p = rs < 4 ? rs : 12288 + rs; // rows 0..3 and 12292..12295
    hp[((long)b * NP + p) * 256 + ch] = 0;
  }
}

// ---------------- LayerNorm (fp32 in -> bf16 out), one wave per token --------
__global__ __launch_bounds__(256) void ln_k(const float* __restrict__ x,
                                            const float* __restrict__ gw,
                                            const float* __restrict__ bw,
                                            short* __restrict__ out, int pad) {
  const int tid = threadIdx.x, w = tid >> 6, lane = tid & 63;
  const long t = (long)blockIdx.x * 4 + w;
  f32x4 v = *((const f32x4*)(x + t * 256) + lane);
  float s  = v[0] + v[1] + v[2] + v[3];
  float ss = v[0] * v[0] + v[1] * v[1] + v[2] * v[2] + v[3] * v[3];
#pragma unroll
  for (int mk = 1; mk < 64; mk <<= 1) {
    s  += __shfl_xor(s, mk);
    ss += __shfl_xor(ss, mk);
  }
  const float mu   = s * (1.0f / 256.0f);
  const float var  = ss * (1.0f / 256.0f) - mu * mu;
  const float rstd = rsqrtf(var + 1e-5f);
  f32x4 g4 = *((const f32x4*)gw + lane);
  f32x4 b4 = *((const f32x4*)bw + lane);
  const long orow = pad ? (t + (t / Nn) * 8 + 4) : t;   // hp padded layout for LN1
  s16x4 o4;
#pragma unroll
  for (int j = 0; j < 4; ++j) o4[j] = f2bf((v[j] - mu) * rstd * g4[j] + b4[j]);
  *((s16x4*)(out + orow * 256) + lane) = o4;
}

// ---------------- 128x128 GEMM, bf16 MFMA, epilogue variants -----------------
// EPI 0: outS = bf16(acc + bias)
// EPI 1: outF = acc + bias + res   (fp32)
// EPI 2: outS = bf16(gelu(acc + bias))   exact gelu
template <int EPI>
__global__ __launch_bounds__(256, 2) void gemm_k(
    const short* __restrict__ A, int lda,
    const short* __restrict__ Bt,         // [Nout][K] bf16 (pre-transposed)
    const float* __restrict__ bias,
    const float* res, short* outS, float* outF,
    int ldo, int K) {
  __shared__ __align__(16) short As[128][32];
  __shared__ __align__(16) short Bs[128][32];
  const int tid = threadIdx.x, w = tid >> 6, lane = tid & 63;
  const int q = lane >> 4, r16 = lane & 15;
  const long row0 = (long)blockIdx.y * 128;
  const int  col0 = blockIdx.x * 128;
  const int  wr = w >> 1, wc = w & 1;
  f32x4 acc[4][4] = {};

  for (int k0 = 0; k0 < K; k0 += 32) {
    stage_tile(A, row0, lda, k0, As, w, lane);
    stage_tile(Bt, col0, K, k0, Bs, w, lane);
    __syncthreads();
    s16x8 af[4], bfv[4];
#pragma unroll
    for (int m = 0; m < 4; ++m) af[m] = *(const s16x8*)&As[wr * 64 + m * 16 + r16][q * 8];
#pragma unroll
    for (int n = 0; n < 4; ++n) bfv[n] = *(const s16x8*)&Bs[wc * 64 + n * 16 + r16][q * 8];
#pragma unroll
    for (int m = 0; m < 4; ++m)
#pragma unroll
      for (int n = 0; n < 4; ++n) acc[m][n] = MFMA(af[m], bfv[n], acc[m][n]);
    __syncthreads();
  }

  const long orow = row0 + wr * 64;
  const int  ocol = col0 + wc * 64;
#pragma unroll
  for (int n = 0; n < 4; ++n) {
    const int   gc = ocol + n * 16 + r16;
    const float bn = bias[gc];
#pragma unroll
    for (int m = 0; m < 4; ++m) {
      const long gr = orow + m * 16 + q * 4;
#pragma unroll
      for (int r = 0; r < 4; ++r) {
        float v = acc[m][n][r] + bn;
        const long o = (gr + r) * (long)ldo + gc;
        if constexpr (EPI == 0) {
          outS[o] = f2bf(v);
        } else if constexpr (EPI == 1) {
          outF[o] = v + res[o];
        } else {
          float t = 0.5f * v * (1.0f + erff(v * 0.70710678118654752f));
          outS[o] = f2bf(t);
        }
      }
    }
  }
}

// ---------------- conv1d K=9 as 9 accumulating GEMMs over padded h -----------
__global__ __launch_bounds__(256, 2) void conv_k(const short* __restrict__ hp,
                                                 const short* __restrict__ convWt,
                                                 const float* __restrict__ bias,
                                                 short* __restrict__ out) {
  __shared__ __align__(16) short As[128][32];
  __shared__ __align__(16) short Bs[128][32];
  const int tid = threadIdx.x, w = tid >> 6, lane = tid & 63;
  const int q = lane >> 4, r16 = lane & 15;
  const long row0 = (long)blockIdx.y * 128;
  const int  col0 = blockIdx.x * 128;
  const int  b  = (int)(row0 / Nn);
  const int  n0 = (int)(row0 % Nn);           // 12288 % 128 == 0: blocks never cross batches
  const long hpbase = (long)b * NP + n0;
  const int  wr = w >> 1, wc = w & 1;
  f32x4 acc[4][4] = {};

  for (int k = 0; k < 9; ++k) {
    const short* Ak = hp + (hpbase + k) * 256; // hp row n+k == token shift n+k-4
    const short* Bk = convWt + k * 65536;
    for (int k0 = 0; k0 < 256; k0 += 32) {
      stage_tile(Ak, 0, 256, k0, As, w, lane);
      stage_tile(Bk, col0, 256, k0, Bs, w, lane);
      __syncthreads();
      s16x8 af[4], bfv[4];
#pragma unroll
      for (int m = 0; m < 4; ++m) af[m] = *(const s16x8*)&As[wr * 64 + m * 16 + r16][q * 8];
#pragma unroll
      for (int n = 0; n < 4; ++n) bfv[n] = *(const s16x8*)&Bs[wc * 64 + n * 16 + r16][q * 8];
#pragma unroll
      for (int m = 0; m < 4; ++m)
#pragma unroll
        for (int n = 0; n < 4; ++n) acc[m][n] = MFMA(af[m], bfv[n], acc[m][n]);
      __syncthreads();
    }
  }

  const long orow = row0 + wr * 64;
  const int  ocol = col0 + wc * 64;
#pragma unroll
  for (int n = 0; n < 4; ++n) {
    const int   gc = ocol + n * 16 + r16;
    const float bn = bias[gc];
#pragma unroll
    for (int m = 0; m < 4; ++m) {
      const long gr = orow + m * 16 + q * 4;
#pragma unroll
      for (int r = 0; r < 4; ++r) out[(gr + r) * 256L + gc] = f2bf(acc[m][n][r] + bn);
    }
  }
}

// ---------------- windowed attention: one wave per (window, head) ------------
__global__ __launch_bounds__(256, 2) void attn_k(const short* __restrict__ qkv,
                                                 short* __restrict__ o) {
  __shared__ __align__(16) short Pt[4][64][68];  // P^T: [j][i], padded stride
  __shared__ __align__(16) short Vs[4][64][32];  // V:   [j][ch], linear (gld16 dest)
  const int tid = threadIdx.x, w = tid >> 6, lane = tid & 63;
  const int q = lane >> 4, r16 = lane & 15;
  const int job = blockIdx.x * 4 + w;
  const int win = job >> 3, h = job & 7;
  const short* base = qkv + (long)win * 64 * 768;

  // stage V (issue early; completes under QK^T + softmax)
#pragma unroll
  for (int c = 0; c < 4; ++c) {
    const int idx16 = c * 64 + lane;
    const short* g = base + (long)(idx16 >> 2) * 768 + 512 + h * 32 + (idx16 & 3) * 8;
    gld16(g, (char*)&Vs[w][0][0] + c * 1024);
  }

  // QK^T straight from global (K-dim = 32 channels, contiguous 16B frags)
  s16x8 aq[4], bk[4];
#pragma unroll
  for (int m = 0; m < 4; ++m)
    aq[m] = *(const s16x8*)(base + (long)(m * 16 + r16) * 768 + h * 32 + q * 8);
#pragma unroll
  for (int n = 0; n < 4; ++n)
    bk[n] = *(const s16x8*)(base + (long)(n * 16 + r16) * 768 + 256 + h * 32 + q * 8);
  f32x4 sc[4][4] = {};
#pragma unroll
  for (int m = 0; m < 4; ++m)
#pragma unroll
    for (int n = 0; n < 4; ++n) sc[m][n] = MFMA(aq[m], bk[n], sc[m][n]);

  // in-register softmax over j (cols spread across n-frags and 16 lanes)
  const float scale = 0.17677669529663687f;  // 32^-0.5
#pragma unroll
  for (int m = 0; m < 4; ++m) {
#pragma unroll
    for (int r = 0; r < 4; ++r) {
      float a0 = sc[m][0][r] * scale, a1 = sc[m][1][r] * scale;
      float a2 = sc[m][2][r] * scale, a3 = sc[m][3][r] * scale;
      float mx = fmaxf(fmaxf(a0, a1), fmaxf(a2, a3));
      mx = fmaxf(mx, __shfl_xor(mx, 1));
      mx = fmaxf(mx, __shfl_xor(mx, 2));
      mx = fmaxf(mx, __shfl_xor(mx, 4));
      mx = fmaxf(mx, __shfl_xor(mx, 8));
      float e0 = __expf(a0 - mx), e1 = __expf(a1 - mx);
      float e2 = __expf(a2 - mx), e3 = __expf(a3 - mx);
      float sm = e0 + e1 + e2 + e3;
      sm += __shfl_xor(sm, 1);
      sm += __shfl_xor(sm, 2);
      sm += __shfl_xor(sm, 4);
      sm += __shfl_xor(sm, 8);
      float inv = 1.0f / sm;
      sc[m][0][r] = e0 * inv; sc[m][1][r] = e1 * inv;
      sc[m][2][r] = e2 * inv; sc[m][3][r] = e3 * inv;
    }
  }

  // write P^T (packed short4: rows i consecutive along Pt's inner dim)
#pragma unroll
  for (int m = 0; m < 4; ++m)
#pragma unroll
    for (int n = 0; n < 4; ++n) {
      s16x4 p4;
#pragma unroll
      for (int r = 0; r < 4; ++r) p4[r] = f2bf(sc[m][n][r]);
      *(s16x4*)&Pt[w][n * 16 + r16][m * 16 + q * 4] = p4;
    }

  asm volatile("s_waitcnt vmcnt(0)" ::: "memory");  // Vs staged

  // PV: O[i][ch] = sum_j P[i][j] V[j][ch]
  f32x4 oa[4][2] = {};
#pragma unroll
  for (int ks = 0; ks < 2; ++ks) {
    s16x8 bv[2];
#pragma unroll
    for (int nt = 0; nt < 2; ++nt)
#pragma unroll
      for (int jj = 0; jj < 8; ++jj)
        bv[nt][jj] = Vs[w][ks * 32 + q * 8 + jj][nt * 16 + r16];
#pragma unroll
    for (int m = 0; m < 4; ++m) {
      s16x8 ap;
#pragma unroll
      for (int jj = 0; jj < 8; ++jj)
        ap[jj] = Pt[w][ks * 32 + q * 8 + jj][m * 16 + r16];
#pragma unroll
      for (int nt = 0; nt < 2; ++nt) oa[m][nt] = MFMA(ap, bv[nt], oa[m][nt]);
    }
  }

  short* ob = o + (long)win * 64 * 256 + h * 32;
#pragma unroll
  for (int m = 0; m < 4; ++m)
#pragma unroll
    for (int nt = 0; nt < 2; ++nt)
#pragma unroll
      for (int r = 0; r < 4; ++r)
        ob[(long)(m * 16 + q * 4 + r) * 256 + nt * 16 + r16] = f2bf(oa[m][nt][r]);
}

// -----------------------------------------------------------------------------
extern "C" void kernel_launch(void* const* d_in, const int* in_sizes, int n_in,
                              void* d_out, int out_size, void* d_ws, size_t ws_size,
                              hipStream_t stream) {
  const float* x      = (const float*)d_in[0];
  const float* ln1_g  = (const float*)d_in[1];
  const float* ln1_b  = (const float*)d_in[2];
  const float* conv_w = (const float*)d_in[3];
  const float* conv_b = (const float*)d_in[4];
  const float* qkv_w  = (const float*)d_in[5];
  const float* qkv_b  = (const float*)d_in[6];
  const float* proj_w = (const float*)d_in[7];
  const float* proj_b = (const float*)d_in[8];
  const float* ln2_g  = (const float*)d_in[9];
  const float* ln2_b  = (const float*)d_in[10];
  const float* fc1_w  = (const float*)d_in[11];
  const float* fc1_b  = (const float*)d_in[12];
  const float* fc2_w  = (const float*)d_in[13];
  const float* fc2_b  = (const float*)d_in[14];
  float* out = (float*)d_out;

  // workspace layout (shorts). hp region is reused: h(padded) -> attn_out -> ln2_out.
  // hidden (TOK x 1024) exactly spans qkv (TOK x 768) + conv_out (TOK x 256).
  constexpr long HPsz = (long)8 * NP * 256;   // 25,182,208
  constexpr long Qsz  = TOK * 768;            // 75,497,472
  constexpr long Csz  = TOK * 256;            // 25,165,824
  short* ws    = (short*)d_ws;
  short* hp    = ws;
  short* qkvB  = ws + HPsz;
  short* cvB   = ws + HPsz + Qsz;
  short* hidB  = qkvB;                        // aliases qkvB+cvB (both dead by then)
  short* wts   = ws + HPsz + Qsz + Csz;
  short* qkvWt  = wts;
  short* projWt = qkvWt + 196608;
  short* fc1Wt  = projWt + 65536;
  short* fc2Wt  = fc1Wt + 262144;
  short* convWt = fc2Wt + 262144;

  prep_k<<<5440, 256, 0, stream>>>(qkv_w, proj_w, fc1_w, fc2_w, conv_w,
                                   qkvWt, projWt, fc1Wt, fc2Wt, convWt, hp);
  // LN1 -> hp (padded layout)
  ln_k<<<24576, 256, 0, stream>>>(x, ln1_g, ln1_b, hp, 1);
  // conv1d -> conv_out (bf16)
  conv_k<<<dim3(2, 768), 256, 0, stream>>>(hp, convWt, conv_b, cvB);
  // qkv GEMM -> qkvB (bf16, ld 768)
  gemm_k<0><<<dim3(6, 768), 256, 0, stream>>>(cvB, 256, qkvWt, qkv_b,
                                              nullptr, qkvB, nullptr, 768, 256);
  // windowed attention -> hp region (attn_out, [t][256])
  attn_k<<<3072, 256, 0, stream>>>(qkvB, hp);
  // proj + residual(x) -> d_out (= x1, fp32)
  gemm_k<1><<<dim3(2, 768), 256, 0, stream>>>(hp, 256, projWt, proj_b,
                                              x, nullptr, out, 256, 256);
  // LN2(x1) -> hp region (bf16)
  ln_k<<<24576, 256, 0, stream>>>(out, ln2_g, ln2_b, hp, 0);
  // fc1 + exact GELU -> hidden (bf16, ld 1024)
  gemm_k<2><<<dim3(8, 768), 256, 0, stream>>>(hp, 256, fc1Wt, fc1_b,
                                              nullptr, hidB, nullptr, 1024, 256);
  // fc2 + residual(x1 in d_out) -> d_out
  gemm_k<1><<<dim3(2, 768), 256, 0, stream>>>(hidB, 1024, fc2Wt, fc2_b,
                                              out, nullptr, out, 256, 1024);
}

// Round 2
// 671.338 us; speedup vs baseline: 1.1034x; 1.1034x over previous
//
#include <hip/hip_runtime.h>

#define DEVI __device__ __forceinline__

typedef __attribute__((ext_vector_type(4))) float  f32x4;
typedef __attribute__((ext_vector_type(8))) short  s16x8;
typedef __attribute__((ext_vector_type(4))) short  s16x4;
typedef __attribute__((ext_vector_type(8))) __bf16 bf16x8;

constexpr int  Nn  = 12288;
constexpr int  NP  = 12296;          // padded rows per batch (4 + 12288 + 4)
constexpr long TOK = 98304;          // B*D*N

DEVI short f2bf(float f) {           // fp32 -> bf16 (RTNE), bits as short
  unsigned u = __builtin_bit_cast(unsigned, f);
  u += 0x7fffu + ((u >> 16) & 1u);
  return (short)(u >> 16);
}

DEVI f32x4 MFMA(s16x8 a, s16x8 b, f32x4 c) {
  return __builtin_amdgcn_mfma_f32_16x16x32_bf16(
      __builtin_bit_cast(bf16x8, a), __builtin_bit_cast(bf16x8, b), c, 0, 0, 0);
}

DEVI void gld16(const void* g, void* l) {   // global -> LDS, 16B/lane, linear dest
  __builtin_amdgcn_global_load_lds(
      (const __attribute__((address_space(1))) void*)g,
      (__attribute__((address_space(3))) void*)l, 16, 0, 0);
}

// Stage a [UNITS*2][64] bf16 tile into LDS (16B units, 8 units/row).
// Wave-uniform LDS base + lane*16 (hardware); per-lane global source.
template <int UNITS>
DEVI void stage64(const short* __restrict__ g_base, long g_row0, int ld, int k0,
                  short* __restrict__ lds, int w, int lane) {
#pragma unroll
  for (int cc = 0; cc < UNITS; ++cc) {
    const int u = cc * 256 + w * 64 + lane;
    const int row = u >> 3, ch = u & 7;
    const short* g = g_base + (g_row0 + row) * (long)ld + k0 + ch * 8;
    gld16(g, lds + (cc * 256 + w * 64) * 8);
  }
}

DEVI void xcd_decode(int W, int total, int ncol, long& row0, int& col0) {
  const int per = total >> 3;                 // total % 8 == 0 (all our grids)
  const int L = (W & 7) * per + (W >> 3);     // bijective chunked XCD swizzle
  row0 = (long)(L / ncol) * 128;
  col0 = (L % ncol) * 128;
}

// ---------------- weight prep + halo-pad zeroing (one launch) ----------------
__global__ void prep_k(const float* __restrict__ qkv_w, const float* __restrict__ proj_w,
                       const float* __restrict__ fc1_w, const float* __restrict__ fc2_w,
                       const float* __restrict__ conv_w,
                       short* __restrict__ qkvWt, short* __restrict__ projWt,
                       short* __restrict__ fc1Wt, short* __restrict__ fc2Wt,
                       short* __restrict__ convWt, short* __restrict__ hp) {
  int idx = blockIdx.x * 256 + threadIdx.x;
  if (idx < 196608) {                 // qkvWt [768][256] <- qkv_w (256,768)
    int o = idx >> 8, i = idx & 255;
    qkvWt[idx] = f2bf(qkv_w[i * 768 + o]);
    return;
  }
  idx -= 196608;
  if (idx < 65536) {                  // projWt [256][256]
    int o = idx >> 8, i = idx & 255;
    projWt[idx] = f2bf(proj_w[i * 256 + o]);
    return;
  }
  idx -= 65536;
  if (idx < 262144) {                 // fc1Wt [1024][256]
    int o = idx >> 8, i = idx & 255;
    fc1Wt[idx] = f2bf(fc1_w[i * 1024 + o]);
    return;
  }
  idx -= 262144;
  if (idx < 262144) {                 // fc2Wt [256][1024]
    int o = idx >> 10, i = idx & 1023;
    fc2Wt[idx] = f2bf(fc2_w[i * 256 + o]);
    return;
  }
  idx -= 262144;
  if (idx < 589824) {                 // convWt [co][k][ci] <- conv_w (co,ci,k)
    int co = idx / 2304, rem = idx % 2304;
    int k = rem >> 8, ci = rem & 255;
    convWt[idx] = f2bf(conv_w[co * 2304 + ci * 9 + k]);
    return;
  }
  idx -= 589824;
  if (idx < 16384) {                  // zero halo pads of hp
    int b = idx >> 11, rem = idx & 2047;
    int rs = rem >> 8, ch = rem & 255;
    int p = rs < 4 ? rs : 12288 + rs; // rows 0..3 and 12292..12295
    hp[((long)b * NP + p) * 256 + ch] = 0;
  }
}

// ---------------- LayerNorm (fp32 in -> bf16 out), one wave per token --------
__global__ __launch_bounds__(256) void ln_k(const float* __restrict__ x,
                                            const float* __restrict__ gw,
                                            const float* __restrict__ bw,
                                            short* __restrict__ out) {
  const int tid = threadIdx.x, w = tid >> 6, lane = tid & 63;
  const long t = (long)blockIdx.x * 4 + w;
  f32x4 v = *((const f32x4*)(x + t * 256) + lane);
  float s  = v[0] + v[1] + v[2] + v[3];
  float ss = v[0] * v[0] + v[1] * v[1] + v[2] * v[2] + v[3] * v[3];
#pragma unroll
  for (int mk = 1; mk < 64; mk <<= 1) {
    s  += __shfl_xor(s, mk);
    ss += __shfl_xor(ss, mk);
  }
  const float mu   = s * (1.0f / 256.0f);
  const float var  = ss * (1.0f / 256.0f) - mu * mu;
  const float rstd = rsqrtf(var + 1e-5f);
  f32x4 g4 = *((const f32x4*)gw + lane);
  f32x4 b4 = *((const f32x4*)bw + lane);
  const long orow = t + (t / Nn) * 8 + 4;    // hp padded layout
  s16x4 o4;
#pragma unroll
  for (int j = 0; j < 4; ++j) o4[j] = f2bf((v[j] - mu) * rstd * g4[j] + b4[j]);
  *((s16x4*)(out + orow * 256) + lane) = o4;
}

// ---------------- 128x128 GEMM, BK=64, bf16 MFMA, epilogue variants ----------
// EPI 0: outS = bf16(acc + bias)
// EPI 1: outF = acc + bias + res   (fp32)
// EPI 2: outS = bf16(gelu(acc + bias))   exact gelu
template <int EPI>
__global__ __launch_bounds__(256, 2) void gemm_k(
    const short* __restrict__ A, int lda,
    const short* __restrict__ Bt,         // [Nout][K] bf16 (pre-transposed)
    const float* __restrict__ bias,
    const float* res, short* outS, float* outF,
    int ldo, int K, int ncol) {
  __shared__ __align__(16) short As[128][64];
  __shared__ __align__(16) short Bs[128][64];
  const int tid = threadIdx.x, w = tid >> 6, lane = tid & 63;
  const int q = lane >> 4, r16 = lane & 15;
  long row0; int col0;
  xcd_decode(blockIdx.x, gridDim.x, ncol, row0, col0);
  const int wr = w >> 1, wc = w & 1;
  f32x4 acc[4][4] = {};

  for (int k0 = 0; k0 < K; k0 += 64) {
    stage64<4>(A, row0, lda, k0, &As[0][0], w, lane);
    stage64<4>(Bt, col0, K, k0, &Bs[0][0], w, lane);
    __syncthreads();
#pragma unroll
    for (int kk = 0; kk < 2; ++kk) {
      s16x8 af[4], bfv[4];
#pragma unroll
      for (int m = 0; m < 4; ++m) af[m] = *(const s16x8*)&As[wr * 64 + m * 16 + r16][kk * 32 + q * 8];
#pragma unroll
      for (int n = 0; n < 4; ++n) bfv[n] = *(const s16x8*)&Bs[wc * 64 + n * 16 + r16][kk * 32 + q * 8];
#pragma unroll
      for (int m = 0; m < 4; ++m)
#pragma unroll
        for (int n = 0; n < 4; ++n) acc[m][n] = MFMA(af[m], bfv[n], acc[m][n]);
    }
    __syncthreads();
  }

  const long orow = row0 + wr * 64;
  const int  ocol = col0 + wc * 64;
#pragma unroll
  for (int n = 0; n < 4; ++n) {
    const int   gc = ocol + n * 16 + r16;
    const float bn = bias[gc];
#pragma unroll
    for (int m = 0; m < 4; ++m) {
      const long gr = orow + m * 16 + q * 4;
#pragma unroll
      for (int r = 0; r < 4; ++r) {
        float v = acc[m][n][r] + bn;
        const long o = (gr + r) * (long)ldo + gc;
        if constexpr (EPI == 0) {
          outS[o] = f2bf(v);
        } else if constexpr (EPI == 1) {
          outF[o] = v + res[o];
        } else {
          float t = 0.5f * v * (1.0f + erff(v * 0.70710678118654752f));
          outS[o] = f2bf(t);
        }
      }
    }
  }
}

// ---------------- conv1d K=9: A held across taps (halo-staged), BK=64 --------
__global__ __launch_bounds__(256, 2) void conv_k(const short* __restrict__ hp,
                                                 const short* __restrict__ convWt,
                                                 const float* __restrict__ bias,
                                                 short* __restrict__ out) {
  __shared__ __align__(16) short As[160][64];   // rows n0..n0+159 (need +135), held per k0
  __shared__ __align__(16) short Bs[128][64];
  const int tid = threadIdx.x, w = tid >> 6, lane = tid & 63;
  const int q = lane >> 4, r16 = lane & 15;
  long row0; int col0;
  xcd_decode(blockIdx.x, gridDim.x, 2, row0, col0);
  const int  b  = (int)(row0 / Nn);
  const int  n0 = (int)(row0 % Nn);            // 12288 % 128 == 0: never crosses batches
  const long abase = (long)b * NP + n0;        // hp row n0+r == token n0+r-4 shift
  const int  wr = w >> 1, wc = w & 1;
  f32x4 acc[4][4] = {};

  for (int k0 = 0; k0 < 256; k0 += 64) {
    stage64<5>(hp, abase, 256, k0, &As[0][0], w, lane);    // 160 rows (24 garbage, unread)
    for (int tap = 0; tap < 9; ++tap) {
      stage64<4>(convWt, col0, 2304, tap * 256 + k0, &Bs[0][0], w, lane);
      __syncthreads();
#pragma unroll
      for (int kk = 0; kk < 2; ++kk) {
        s16x8 af[4], bfv[4];
#pragma unroll
        for (int m = 0; m < 4; ++m)
          af[m] = *(const s16x8*)&As[tap + wr * 64 + m * 16 + r16][kk * 32 + q * 8];
#pragma unroll
        for (int n = 0; n < 4; ++n)
          bfv[n] = *(const s16x8*)&Bs[wc * 64 + n * 16 + r16][kk * 32 + q * 8];
#pragma unroll
        for (int m = 0; m < 4; ++m)
#pragma unroll
          for (int n = 0; n < 4; ++n) acc[m][n] = MFMA(af[m], bfv[n], acc[m][n]);
      }
      __syncthreads();
    }
  }

  const long orow = row0 + wr * 64;
  const int  ocol = col0 + wc * 64;
#pragma unroll
  for (int n = 0; n < 4; ++n) {
    const int   gc = ocol + n * 16 + r16;
    const float bn = bias[gc];
#pragma unroll
    for (int m = 0; m < 4; ++m) {
      const long gr = orow + m * 16 + q * 4;
#pragma unroll
      for (int r = 0; r < 4; ++r) out[(gr + r) * 256L + gc] = f2bf(acc[m][n][r] + bn);
    }
  }
}

// ------- proj GEMM (tile 128x256 = full C) + residual + fused LayerNorm2 -----
__global__ __launch_bounds__(256, 2) void proj_ln_k(
    const short* __restrict__ A,          // attn_out bf16 [TOK][256]
    const short* __restrict__ Bt,         // projWt [256][256]
    const float* __restrict__ bias,
    const float* __restrict__ res,        // x (fp32)
    const float* __restrict__ gw, const float* __restrict__ bw,
    float* __restrict__ x1,               // fp32 out (d_out)
    short* __restrict__ lnout) {          // bf16 LN2 output
  __shared__ __align__(16) short As[128][64];
  __shared__ __align__(16) short Bs[256][64];
  __shared__ float red[2][128][2];
  const int tid = threadIdx.x, w = tid >> 6, lane = tid & 63;
  const int q = lane >> 4, r16 = lane & 15;
  const int W = blockIdx.x, per = gridDim.x >> 3;
  const long row0 = (long)((W & 7) * per + (W >> 3)) * 128;
  const int wr = w >> 1, wc = w & 1;      // wave tile 64 rows x 128 cols
  f32x4 acc[4][8] = {};

  for (int k0 = 0; k0 < 256; k0 += 64) {
    stage64<4>(A, row0, 256, k0, &As[0][0], w, lane);
    stage64<8>(Bt, 0, 256, k0, &Bs[0][0], w, lane);
    __syncthreads();
#pragma unroll
    for (int kk = 0; kk < 2; ++kk) {
      s16x8 af[4], bfv[8];
#pragma unroll
      for (int m = 0; m < 4; ++m) af[m] = *(const s16x8*)&As[wr * 64 + m * 16 + r16][kk * 32 + q * 8];
#pragma unroll
      for (int n = 0; n < 8; ++n) bfv[n] = *(const s16x8*)&Bs[wc * 128 + n * 16 + r16][kk * 32 + q * 8];
#pragma unroll
      for (int m = 0; m < 4; ++m)
#pragma unroll
        for (int n = 0; n < 8; ++n) acc[m][n] = MFMA(af[m], bfv[n], acc[m][n]);
    }
    __syncthreads();
  }

  // epilogue: x1 = acc + bias + res; row stats; LN2
  float s[4][4] = {}, ss[4][4] = {};
#pragma unroll
  for (int n = 0; n < 8; ++n) {
    const int   gc = wc * 128 + n * 16 + r16;
    const float bn = bias[gc];
#pragma unroll
    for (int m = 0; m < 4; ++m) {
#pragma unroll
      for (int r = 0; r < 4; ++r) {
        const long gr = row0 + wr * 64 + m * 16 + q * 4 + r;
        float v = acc[m][n][r] + bn + res[gr * 256 + gc];
        acc[m][n][r] = v;
        x1[gr * 256 + gc] = v;
        s[m][r] += v;
        ss[m][r] += v * v;
      }
    }
  }
#pragma unroll
  for (int m = 0; m < 4; ++m)
#pragma unroll
    for (int r = 0; r < 4; ++r) {
#pragma unroll
      for (int mk = 1; mk < 16; mk <<= 1) {
        s[m][r]  += __shfl_xor(s[m][r], mk);
        ss[m][r] += __shfl_xor(ss[m][r], mk);
      }
      if (r16 == 0) {
        const int lr = wr * 64 + m * 16 + q * 4 + r;
        red[wc][lr][0] = s[m][r];
        red[wc][lr][1] = ss[m][r];
      }
    }
  __syncthreads();
#pragma unroll
  for (int m = 0; m < 4; ++m)
#pragma unroll
    for (int r = 0; r < 4; ++r) {
      const int  lr = wr * 64 + m * 16 + q * 4 + r;
      const long gr = row0 + lr;
      const float S  = red[0][lr][0] + red[1][lr][0];
      const float SS = red[0][lr][1] + red[1][lr][1];
      const float mu = S * (1.0f / 256.0f);
      const float rstd = rsqrtf(SS * (1.0f / 256.0f) - mu * mu + 1e-5f);
#pragma unroll
      for (int n = 0; n < 8; ++n) {
        const int gc = wc * 128 + n * 16 + r16;
        lnout[gr * 256 + gc] = f2bf((acc[m][n][r] - mu) * rstd * gw[gc] + bw[gc]);
      }
    }
}

// ---------------- windowed attention: one wave per (window, head) ------------
__global__ __launch_bounds__(256, 2) void attn_k(const short* __restrict__ qkv,
                                                 short* __restrict__ o) {
  __shared__ __align__(16) short Pt[4][64][68];  // P^T: [j][i], padded stride
  __shared__ __align__(16) short Vs[4][64][32];  // V:   [j][ch], linear (gld16 dest)
  const int tid = threadIdx.x, w = tid >> 6, lane = tid & 63;
  const int q = lane >> 4, r16 = lane & 15;
  const int job = blockIdx.x * 4 + w;
  const int win = job >> 3, h = job & 7;
  const short* base = qkv + (long)win * 64 * 768;

#pragma unroll
  for (int c = 0; c < 4; ++c) {
    const int idx16 = c * 64 + lane;
    const short* g = base + (long)(idx16 >> 2) * 768 + 512 + h * 32 + (idx16 & 3) * 8;
    gld16(g, (char*)&Vs[w][0][0] + c * 1024);
  }

  s16x8 aq[4], bk[4];
#pragma unroll
  for (int m = 0; m < 4; ++m)
    aq[m] = *(const s16x8*)(base + (long)(m * 16 + r16) * 768 + h * 32 + q * 8);
#pragma unroll
  for (int n = 0; n < 4; ++n)
    bk[n] = *(const s16x8*)(base + (long)(n * 16 + r16) * 768 + 256 + h * 32 + q * 8);
  f32x4 sc[4][4] = {};
#pragma unroll
  for (int m = 0; m < 4; ++m)
#pragma unroll
    for (int n = 0; n < 4; ++n) sc[m][n] = MFMA(aq[m], bk[n], sc[m][n]);

  const float scale = 0.17677669529663687f;  // 32^-0.5
#pragma unroll
  for (int m = 0; m < 4; ++m) {
#pragma unroll
    for (int r = 0; r < 4; ++r) {
      float a0 = sc[m][0][r] * scale, a1 = sc[m][1][r] * scale;
      float a2 = sc[m][2][r] * scale, a3 = sc[m][3][r] * scale;
      float mx = fmaxf(fmaxf(a0, a1), fmaxf(a2, a3));
      mx = fmaxf(mx, __shfl_xor(mx, 1));
      mx = fmaxf(mx, __shfl_xor(mx, 2));
      mx = fmaxf(mx, __shfl_xor(mx, 4));
      mx = fmaxf(mx, __shfl_xor(mx, 8));
      float e0 = __expf(a0 - mx), e1 = __expf(a1 - mx);
      float e2 = __expf(a2 - mx), e3 = __expf(a3 - mx);
      float sm = e0 + e1 + e2 + e3;
      sm += __shfl_xor(sm, 1);
      sm += __shfl_xor(sm, 2);
      sm += __shfl_xor(sm, 4);
      sm += __shfl_xor(sm, 8);
      float inv = 1.0f / sm;
      sc[m][0][r] = e0 * inv; sc[m][1][r] = e1 * inv;
      sc[m][2][r] = e2 * inv; sc[m][3][r] = e3 * inv;
    }
  }

#pragma unroll
  for (int m = 0; m < 4; ++m)
#pragma unroll
    for (int n = 0; n < 4; ++n) {
      s16x4 p4;
#pragma unroll
      for (int r = 0; r < 4; ++r) p4[r] = f2bf(sc[m][n][r]);
      *(s16x4*)&Pt[w][n * 16 + r16][m * 16 + q * 4] = p4;
    }

  asm volatile("s_waitcnt vmcnt(0)" ::: "memory");  // Vs staged

  f32x4 oa[4][2] = {};
#pragma unroll
  for (int ks = 0; ks < 2; ++ks) {
    s16x8 bv[2];
#pragma unroll
    for (int nt = 0; nt < 2; ++nt)
#pragma unroll
      for (int jj = 0; jj < 8; ++jj)
        bv[nt][jj] = Vs[w][ks * 32 + q * 8 + jj][nt * 16 + r16];
#pragma unroll
    for (int m = 0; m < 4; ++m) {
      s16x8 ap;
#pragma unroll
      for (int jj = 0; jj < 8; ++jj)
        ap[jj] = Pt[w][ks * 32 + q * 8 + jj][m * 16 + r16];
#pragma unroll
      for (int nt = 0; nt < 2; ++nt) oa[m][nt] = MFMA(ap, bv[nt], oa[m][nt]);
    }
  }

  short* ob = o + (long)win * 64 * 256 + h * 32;
#pragma unroll
  for (int m = 0; m < 4; ++m)
#pragma unroll
    for (int nt = 0; nt < 2; ++nt)
#pragma unroll
      for (int r = 0; r < 4; ++r)
        ob[(long)(m * 16 + q * 4 + r) * 256 + nt * 16 + r16] = f2bf(oa[m][nt][r]);
}

// -----------------------------------------------------------------------------
extern "C" void kernel_launch(void* const* d_in, const int* in_sizes, int n_in,
                              void* d_out, int out_size, void* d_ws, size_t ws_size,
                              hipStream_t stream) {
  const float* x      = (const float*)d_in[0];
  const float* ln1_g  = (const float*)d_in[1];
  const float* ln1_b  = (const float*)d_in[2];
  const float* conv_w = (const float*)d_in[3];
  const float* conv_b = (const float*)d_in[4];
  const float* qkv_w  = (const float*)d_in[5];
  const float* qkv_b  = (const float*)d_in[6];
  const float* proj_w = (const float*)d_in[7];
  const float* proj_b = (const float*)d_in[8];
  const float* ln2_g  = (const float*)d_in[9];
  const float* ln2_b  = (const float*)d_in[10];
  const float* fc1_w  = (const float*)d_in[11];
  const float* fc1_b  = (const float*)d_in[12];
  const float* fc2_w  = (const float*)d_in[13];
  const float* fc2_b  = (const float*)d_in[14];
  float* out = (float*)d_out;

  // workspace layout (shorts). hp region reused: h(padded) -> attn_out -> ln2_out.
  constexpr long HPsz = (long)8 * NP * 256;   // 25,182,208
  constexpr long Qsz  = TOK * 768;
  constexpr long Csz  = TOK * 256;
  short* ws    = (short*)d_ws;
  short* hp    = ws;
  short* qkvB  = ws + HPsz;
  short* cvB   = ws + HPsz + Qsz;
  short* hidB  = qkvB;                        // aliases qkv+conv regions (dead by then)
  short* wts   = ws + HPsz + Qsz + Csz;
  short* qkvWt  = wts;
  short* projWt = qkvWt + 196608;
  short* fc1Wt  = projWt + 65536;
  short* fc2Wt  = fc1Wt + 262144;
  short* convWt = fc2Wt + 262144;

  prep_k<<<5440, 256, 0, stream>>>(qkv_w, proj_w, fc1_w, fc2_w, conv_w,
                                   qkvWt, projWt, fc1Wt, fc2Wt, convWt, hp);
  // LN1 -> hp (padded layout)
  ln_k<<<24576, 256, 0, stream>>>(x, ln1_g, ln1_b, hp);
  // conv1d -> cvB (bf16)
  conv_k<<<1536, 256, 0, stream>>>(hp, convWt, conv_b, cvB);
  // qkv GEMM -> qkvB (bf16, ld 768)
  gemm_k<0><<<4608, 256, 0, stream>>>(cvB, 256, qkvWt, qkv_b,
                                      nullptr, qkvB, nullptr, 768, 256, 6);
  // windowed attention -> hp region (attn_out, [t][256])
  attn_k<<<3072, 256, 0, stream>>>(qkvB, hp);
  // proj + residual(x) + LN2 fused: x1 -> d_out (fp32), ln2 -> hp (bf16)
  proj_ln_k<<<768, 256, 0, stream>>>(hp, projWt, proj_b, x, ln2_g, ln2_b, out, hp);
  // fc1 + exact GELU -> hidden (bf16, ld 1024)
  gemm_k<2><<<6144, 256, 0, stream>>>(hp, 256, fc1Wt, fc1_b,
                                      nullptr, hidB, nullptr, 1024, 256, 8);
  // fc2 + residual(x1 in d_out) -> d_out
  gemm_k<1><<<1536, 256, 0, stream>>>(hidB, 1024, fc2Wt, fc2_b,
                                      out, nullptr, out, 256, 1024, 2);
}